// Round 2
// baseline (327.208 us; speedup 1.0000x reference)
//
#include <hip/hip_runtime.h>

// Problem constants (GlobalPointer: B=16, L=512, H=1024, HEADS=12, D=64)
#define BB 16
#define LL 512
#define HH 1024
#define HEADS 12
#define DD 64
#define N1 1536   // HEADS * 2 * DD
#define M1 8192   // BB * LL
#define NEGC 1e12f

typedef short bf16x8 __attribute__((ext_vector_type(8)));
typedef float f32x4 __attribute__((ext_vector_type(4)));

typedef const __attribute__((address_space(1))) unsigned int glob_u32;
typedef __attribute__((address_space(3))) unsigned int lds_u32;

__device__ __forceinline__ void gl_lds16(const unsigned short* g, unsigned short* l) {
    __builtin_amdgcn_global_load_lds((glob_u32*)g, (lds_u32*)l, 16, 0, 0);
}

__device__ __forceinline__ unsigned short f2bf(float f) {
    union { float f; unsigned int u; } v; v.f = f;
    unsigned int u = v.u;
    return (unsigned short)((u + 0x7fffu + ((u >> 16) & 1u)) >> 16);
}

// ---------------- Kernel 1: X fp32 -> bf16 (8192x1024) ----------------
__global__ __launch_bounds__(256) void k_conv_x(const float* __restrict__ X,
                                                unsigned short* __restrict__ Xb,
                                                int n4) {
    int i = blockIdx.x * 256 + threadIdx.x;
    if (i >= n4) return;
    float4 v = ((const float4*)X)[i];
    ushort4 o;
    o.x = f2bf(v.x); o.y = f2bf(v.y); o.z = f2bf(v.z); o.w = f2bf(v.w);
    ((ushort4*)Xb)[i] = o;
}

// ------------- Kernel 2: W (1024x1536 f32) -> Wt (1536x1024 bf16) -------------
__global__ __launch_bounds__(256) void k_trans_w(const float* __restrict__ W,
                                                 unsigned short* __restrict__ Wt) {
    __shared__ float tile[32][33];
    int n0 = blockIdx.x * 32;
    int k0 = blockIdx.y * 32;
    int tx = threadIdx.x;   // 0..31
    int ty = threadIdx.y;   // 0..7
#pragma unroll
    for (int i = 0; i < 4; i++) {
        int k = ty + i * 8;
        tile[k][tx] = W[(size_t)(k0 + k) * N1 + n0 + tx];
    }
    __syncthreads();
#pragma unroll
    for (int i = 0; i < 4; i++) {
        int n = ty + i * 8;
        Wt[(size_t)(n0 + n) * HH + k0 + tx] = f2bf(tile[tx][n]);
    }
}

// ------------- Kernel 3: C = Xb @ Wt^T (+bias, RoPE) -> Qr, Kr (bf16) -------------
// m97 structure: 128x128 tile, BK=32, 256 thr = 4 waves (2x2), each wave 64x64
// via 4x4 tiles of 16x16x32 MFMA. Staging via global_load_lds width=16 into
// unpadded [128][32] LDS (lane*16B contiguity rule satisfied).
__global__ __launch_bounds__(256) void k_gemm1_rope(
    const unsigned short* __restrict__ Xb,   // [8192][1024]
    const unsigned short* __restrict__ Wt,   // [1536][1024]
    const float* __restrict__ bias,          // [1536]
    const float* __restrict__ pe,            // [512][64]  pe[l][2i]=sin, [2i+1]=cos
    unsigned short* __restrict__ Qr,         // [B*HEADS*512][64]
    unsigned short* __restrict__ Kr)
{
    __shared__ __align__(16) unsigned short As[128 * 32];
    __shared__ __align__(16) unsigned short Bs[128 * 32];
    int m0 = blockIdx.y * 128;
    int n0 = blockIdx.x * 128;
    int tid = threadIdx.x;
    int w  = tid >> 6;
    int ln = tid & 63;
    int lq = ln >> 4;       // quad
    int lm = ln & 15;
    int wm = (w & 1) * 64;
    int wn = (w >> 1) * 64;

    // staging: each wave stages 32 rows of A and 32 rows of B (2 instrs each)
    int lrow = ln >> 2;          // 0..15
    int lcol = (ln & 3) * 8;     // elem offset within 32-elem row
    const unsigned short* ga0 = &Xb[(size_t)(m0 + w * 32 + lrow) * HH + lcol];
    const unsigned short* ga1 = ga0 + (size_t)16 * HH;
    const unsigned short* gb0 = &Wt[(size_t)(n0 + w * 32 + lrow) * HH + lcol];
    const unsigned short* gb1 = gb0 + (size_t)16 * HH;
    unsigned short* la0 = &As[(w * 32) * 32];
    unsigned short* la1 = la0 + 16 * 32;
    unsigned short* lb0 = &Bs[(w * 32) * 32];
    unsigned short* lb1 = lb0 + 16 * 32;

    const unsigned short* pa = &As[(wm + lm) * 32];
    const unsigned short* pb = &Bs[(wn + lm) * 32];

    f32x4 acc[4][4] = {};

    for (int kk = 0; kk < HH; kk += 32) {
        gl_lds16(ga0 + kk, la0);
        gl_lds16(ga1 + kk, la1);
        gl_lds16(gb0 + kk, lb0);
        gl_lds16(gb1 + kk, lb1);
        __syncthreads();   // drains vmcnt(0) before barrier

        bf16x8 af[4], bf[4];
#pragma unroll
        for (int t = 0; t < 4; t++) {
            af[t] = *(const bf16x8*)&pa[t * 16 * 32 + lq * 8];
            bf[t] = *(const bf16x8*)&pb[t * 16 * 32 + lq * 8];
        }
#pragma unroll
        for (int ti = 0; ti < 4; ti++)
#pragma unroll
            for (int tj = 0; tj < 4; tj++)
                acc[ti][tj] = __builtin_amdgcn_mfma_f32_16x16x32_bf16(af[ti], bf[tj], acc[ti][tj], 0, 0, 0);
        __syncthreads();
    }

    // Epilogue: bias + interleaved RoPE, scatter to Qr/Kr as bf16.
#pragma unroll
    for (int tj = 0; tj < 4; tj++) {
        int n = n0 + wn + tj * 16 + lm;        // 0..1535
        float bv = bias[n];
        int h = n >> 7;                         // head
        int c = n & 127;
        int j = c & 63;
        int ii = j >> 1;                        // freq index
        bool isK = (c >= 64);
        unsigned short* dst = isK ? Kr : Qr;
#pragma unroll
        for (int ti = 0; ti < 4; ti++) {
#pragma unroll
            for (int r = 0; r < 4; r++) {
                int m = m0 + wm + ti * 16 + lq * 4 + r;   // 0..8191
                int l = m & (LL - 1);
                int bidx = m >> 9;
                float v = acc[ti][tj][r] + bv;
                float vp = __shfl_xor(v, 1, 64);          // pair partner (n^1 == lane^1)
                float2 sc = *(const float2*)&pe[l * 64 + 2 * ii];  // (sin, cos)
                float o = (j & 1) ? (v * sc.y + vp * sc.x) : (v * sc.y - vp * sc.x);
                size_t idx = ((size_t)(bidx * HEADS + h) * LL + l) * DD + j;
                dst[idx] = f2bf(o);
            }
        }
    }
}

// ------------- Kernel 4: logits = Q @ K^T, mask, /8 -------------
// Swapped-operand MFMA: D = mfma(Kfrag, Qfrag) so col(lane&15)=m, row(quad*4+r)=n
// -> each lane's f32x4 is 4 consecutive n -> float4 stores.
__global__ __launch_bounds__(256) void k_gemm2(
    const unsigned short* __restrict__ Qr,
    const unsigned short* __restrict__ Kr,
    const int* __restrict__ mask,            // [B][L]
    float* __restrict__ out)                 // [B][HEADS][L][L]
{
    __shared__ __align__(16) unsigned short Qs[64 * 72];
    __shared__ __align__(16) unsigned short Ks[64 * 72];
    int bh = blockIdx.z;
    int b  = bh / HEADS;
    int n0 = blockIdx.x * 64;
    int m0 = blockIdx.y * 64;
    int tid = threadIdx.x;
    int w  = tid >> 6;
    int ln = tid & 63;
    int lq = ln >> 4;
    int lm = ln & 15;
    int mw = (w & 1) * 32;
    int nw = (w >> 1) * 32;

    const unsigned short* Qb = Qr + (size_t)bh * LL * DD;
    const unsigned short* Kb = Kr + (size_t)bh * LL * DD;

    int srow = tid >> 3;          // 0..31
    int scol = (tid & 7) * 8;     // 0..56
#pragma unroll
    for (int p = 0; p < 2; p++) {
        int row = srow + p * 32;
        *(uint4*)&Qs[row * 72 + scol] = *(const uint4*)&Qb[(size_t)(m0 + row) * DD + scol];
        *(uint4*)&Ks[row * 72 + scol] = *(const uint4*)&Kb[(size_t)(n0 + row) * DD + scol];
    }
    __syncthreads();

    f32x4 acc[2][2] = {};   // [tm][tn]
#pragma unroll
    for (int kk = 0; kk < 64; kk += 32) {
        bf16x8 q0 = *(const bf16x8*)&Qs[(mw + lm) * 72 + kk + lq * 8];
        bf16x8 q1 = *(const bf16x8*)&Qs[(mw + 16 + lm) * 72 + kk + lq * 8];
        bf16x8 k0 = *(const bf16x8*)&Ks[(nw + lm) * 72 + kk + lq * 8];
        bf16x8 k1 = *(const bf16x8*)&Ks[(nw + 16 + lm) * 72 + kk + lq * 8];
        // swapped: D[n][m] layout -> col=lane&15 is m, row=quad*4+r is n
        acc[0][0] = __builtin_amdgcn_mfma_f32_16x16x32_bf16(k0, q0, acc[0][0], 0, 0, 0);
        acc[0][1] = __builtin_amdgcn_mfma_f32_16x16x32_bf16(k1, q0, acc[0][1], 0, 0, 0);
        acc[1][0] = __builtin_amdgcn_mfma_f32_16x16x32_bf16(k0, q1, acc[1][0], 0, 0, 0);
        acc[1][1] = __builtin_amdgcn_mfma_f32_16x16x32_bf16(k1, q1, acc[1][1], 0, 0, 0);
    }

#pragma unroll
    for (int tm = 0; tm < 2; tm++) {
        int m = m0 + mw + tm * 16 + lm;
#pragma unroll
        for (int tn = 0; tn < 2; tn++) {
            int nb = n0 + nw + tn * 16 + lq * 4;
            int4 mv = *(const int4*)&mask[b * LL + nb];
            float4 val;
            {
                float pm = (float)mv.x; int n = nb;
                val.x = (acc[tm][tn][0] * pm - (1.0f - pm) * NEGC - (n < m ? NEGC : 0.0f)) * 0.125f;
            }
            {
                float pm = (float)mv.y; int n = nb + 1;
                val.y = (acc[tm][tn][1] * pm - (1.0f - pm) * NEGC - (n < m ? NEGC : 0.0f)) * 0.125f;
            }
            {
                float pm = (float)mv.z; int n = nb + 2;
                val.z = (acc[tm][tn][2] * pm - (1.0f - pm) * NEGC - (n < m ? NEGC : 0.0f)) * 0.125f;
            }
            {
                float pm = (float)mv.w; int n = nb + 3;
                val.w = (acc[tm][tn][3] * pm - (1.0f - pm) * NEGC - (n < m ? NEGC : 0.0f)) * 0.125f;
            }
            *(float4*)&out[((size_t)bh * LL + m) * LL + nb] = val;
        }
    }
}

extern "C" void kernel_launch(void* const* d_in, const int* in_sizes, int n_in,
                              void* d_out, int out_size, void* d_ws, size_t ws_size,
                              hipStream_t stream) {
    const float* X    = (const float*)d_in[0];   // (16,512,1024)
    const int*   mask = (const int*)d_in[1];     // (16,512)
    const float* W    = (const float*)d_in[2];   // (1024,1536)
    const float* bias = (const float*)d_in[3];   // (1536,)
    const float* pe   = (const float*)d_in[4];   // (512,64)
    float* out = (float*)d_out;

    char* ws = (char*)d_ws;
    unsigned short* Xb = (unsigned short*)ws;                                // 16.78 MB
    unsigned short* Wt = (unsigned short*)(ws + 16777216);                   // 3.15 MB
    unsigned short* Qr = (unsigned short*)(ws + 16777216 + 3145728);         // 12.58 MB
    unsigned short* Kr = Qr + (size_t)BB * HEADS * LL * DD;                  // 12.58 MB

    k_conv_x<<<dim3((M1 * HH / 4 + 255) / 256), dim3(256), 0, stream>>>(X, Xb, M1 * HH / 4);
    k_trans_w<<<dim3(N1 / 32, HH / 32), dim3(32, 8), 0, stream>>>(W, Wt);
    k_gemm1_rope<<<dim3(N1 / 128, M1 / 128), dim3(256), 0, stream>>>(Xb, Wt, bias, pe, Qr, Kr);
    k_gemm2<<<dim3(LL / 64, LL / 64, BB * HEADS), dim3(256), 0, stream>>>(Qr, Kr, mask, out);
}